// Round 1
// baseline (583.967 us; speedup 1.0000x reference)
//
#include <hip/hip_runtime.h>
#include <math.h>

#define BATCH 2
#define SEQ 2048
#define DMODEL 512
#define NH 8
#define HDIM 64
#define MTOT (BATCH * SEQ)              // 4096
#define QSIZE (BATCH * NH * SEQ * HDIM) // 2097152 floats per tensor

// ---------------------------------------------------------------------------
// Kernel 1: fused QKV projection.
// C[m,n] = A[m,:] @ W[:,n] + bias[n], stored into [B, H, S, HD] layout.
// Tiles: 64x64 per block, K-tile 16, 256 threads, 4x4 micro-tile, float4 LDS.
// grid = (N/64=8, M/64=64, 3) ; z selects q/k/v.
// ---------------------------------------------------------------------------
__global__ __launch_bounds__(256) void qkv_proj_kernel(
    const float* __restrict__ qin, const float* __restrict__ kin,
    const float* __restrict__ vin,
    const float* __restrict__ Wq, const float* __restrict__ bq,
    const float* __restrict__ Wk, const float* __restrict__ bk,
    const float* __restrict__ Wv, const float* __restrict__ bv,
    float* __restrict__ ws)
{
    const int which = blockIdx.z;
    const float* A    = (which == 0) ? qin : (which == 1) ? kin : vin;
    const float* W    = (which == 0) ? Wq  : (which == 1) ? Wk  : Wv;
    const float* bias = (which == 0) ? bq  : (which == 1) ? bk  : bv;
    float* out = ws + (size_t)which * QSIZE;

    __shared__ float As[64][20];   // [m][k], pad 20 (80B rows, 16B aligned)
    __shared__ float Wst[64][20];  // [n][k] (transposed W tile)

    const int tid = threadIdx.x;
    const int tx = tid & 15, ty = tid >> 4;
    const int m0 = blockIdx.y * 64, n0 = blockIdx.x * 64;

    float acc[4][4] = {};

    for (int k0 = 0; k0 < DMODEL; k0 += 16) {
        // Load A tile: row = tid>>2 (0..63), 4 k's per thread (float4).
        {
            int mm = tid >> 2, kk = (tid & 3) * 4;
            float4 av = *(const float4*)&A[(size_t)(m0 + mm) * DMODEL + k0 + kk];
            *(float4*)&As[mm][kk] = av;
        }
        // Load W tile transposed: W[k0+r][n0+c] -> Wst[c][r].
        {
            int c = tid & 63;
            int rbase = tid >> 6;
            #pragma unroll
            for (int p = 0; p < 4; ++p) {
                int r = rbase + 4 * p;
                Wst[c][r] = W[(size_t)(k0 + r) * DMODEL + n0 + c];
            }
        }
        __syncthreads();
        for (int k4 = 0; k4 < 16; k4 += 4) {
            float4 a[4], b[4];
            #pragma unroll
            for (int i = 0; i < 4; ++i) a[i] = *(const float4*)&As[ty + 16 * i][k4];
            #pragma unroll
            for (int j = 0; j < 4; ++j) b[j] = *(const float4*)&Wst[tx + 16 * j][k4];
            #pragma unroll
            for (int i = 0; i < 4; ++i)
                #pragma unroll
                for (int j = 0; j < 4; ++j)
                    acc[i][j] += a[i].x * b[j].x + a[i].y * b[j].y +
                                 a[i].z * b[j].z + a[i].w * b[j].w;
        }
        __syncthreads();
    }

    // Store with [B,H,S,HD] layout transform: m=(b,s), n=(h,hd).
    #pragma unroll
    for (int i = 0; i < 4; ++i) {
        int m = m0 + ty + 16 * i;
        int b_ = m >> 11;           // /SEQ
        int s_ = m & (SEQ - 1);
        #pragma unroll
        for (int j = 0; j < 4; ++j) {
            int n = n0 + tx + 16 * j;
            int h_ = n >> 6, hd_ = n & 63;
            float v = acc[i][j] + bias[n];
            out[((size_t)((b_ * NH + h_) * SEQ + s_)) * HDIM + hd_] = v;
        }
    }
}

// ---------------------------------------------------------------------------
// Kernel 2: fp32 flash attention. grid = (B*H=16, S/64=32), 256 threads.
// Q tile 64 rows resident; loop K/V tiles of 64; online softmax.
// LDS: Qs + KPs (K tile aliased with P tile) + Vst = 3*64*68*4 = 52 KB.
// ---------------------------------------------------------------------------
__global__ __launch_bounds__(256) void attn_kernel(
    const float* __restrict__ ws, float* __restrict__ ctx)
{
    const float* Q = ws;
    const float* K = ws + (size_t)QSIZE;
    const float* V = ws + 2 * (size_t)QSIZE;

    __shared__ float Qs[64][68];
    __shared__ float KPs[64][68];  // K tile, then reused as P tile
    __shared__ float Vst[64][68];  // V transposed: [d][key]

    const int bh = blockIdx.x;     // b*NH + h
    const int q0 = blockIdx.y * 64;
    const int tid = threadIdx.x;
    const int tx = tid & 15, ty = tid >> 4;
    const size_t base = (size_t)bh * SEQ * HDIM;

    // Load Q tile, pre-scaled by 1/sqrt(HD)=0.125 (exact, pow2).
    {
        int r = tid >> 2, cbase = (tid & 3) * 16;
        #pragma unroll
        for (int u = 0; u < 4; ++u) {
            int c = cbase + 4 * u;
            float4 v = *(const float4*)&Q[base + (size_t)(q0 + r) * HDIM + c];
            v.x *= 0.125f; v.y *= 0.125f; v.z *= 0.125f; v.w *= 0.125f;
            *(float4*)&Qs[r][c] = v;
        }
    }

    float m_i[4], l_i[4], O[4][4];
    #pragma unroll
    for (int i = 0; i < 4; ++i) {
        m_i[i] = -1e30f; l_i[i] = 0.f;
        #pragma unroll
        for (int j = 0; j < 4; ++j) O[i][j] = 0.f;
    }

    for (int kt = 0; kt < SEQ; kt += 64) {
        __syncthreads();  // prev iter's PV done -> safe to overwrite KPs/Vst
        {
            int r = tid >> 2, cbase = (tid & 3) * 16;
            #pragma unroll
            for (int u = 0; u < 4; ++u) {
                int c = cbase + 4 * u;
                float4 kv = *(const float4*)&K[base + (size_t)(kt + r) * HDIM + c];
                *(float4*)&KPs[r][c] = kv;
                float4 vv = *(const float4*)&V[base + (size_t)(kt + r) * HDIM + c];
                Vst[c + 0][r] = vv.x; Vst[c + 1][r] = vv.y;
                Vst[c + 2][r] = vv.z; Vst[c + 3][r] = vv.w;
            }
        }
        __syncthreads();

        // Scores s[i][j] = Qs[ty+16i][:] . KPs[tx+16j][:]
        float s[4][4] = {};
        for (int d4 = 0; d4 < HDIM; d4 += 4) {
            float4 a[4], b[4];
            #pragma unroll
            for (int i = 0; i < 4; ++i) a[i] = *(const float4*)&Qs[ty + 16 * i][d4];
            #pragma unroll
            for (int j = 0; j < 4; ++j) b[j] = *(const float4*)&KPs[tx + 16 * j][d4];
            #pragma unroll
            for (int i = 0; i < 4; ++i)
                #pragma unroll
                for (int j = 0; j < 4; ++j)
                    s[i][j] += a[i].x * b[j].x + a[i].y * b[j].y +
                               a[i].z * b[j].z + a[i].w * b[j].w;
        }
        __syncthreads();  // all waves done reading K tile -> can alias to P

        // Online softmax per q-row (rows owned by 16 lanes sharing ty).
        #pragma unroll
        for (int i = 0; i < 4; ++i) {
            float rmax = fmaxf(fmaxf(s[i][0], s[i][1]), fmaxf(s[i][2], s[i][3]));
            #pragma unroll
            for (int off = 1; off < 16; off <<= 1)
                rmax = fmaxf(rmax, __shfl_xor(rmax, off, 64));
            float mnew = fmaxf(m_i[i], rmax);
            float alpha = __expf(m_i[i] - mnew);
            float rsum = 0.f;
            #pragma unroll
            for (int j = 0; j < 4; ++j) {
                s[i][j] = __expf(s[i][j] - mnew);
                rsum += s[i][j];
            }
            #pragma unroll
            for (int off = 1; off < 16; off <<= 1)
                rsum += __shfl_xor(rsum, off, 64);
            l_i[i] = l_i[i] * alpha + rsum;
            m_i[i] = mnew;
            #pragma unroll
            for (int j = 0; j < 4; ++j) O[i][j] *= alpha;
            #pragma unroll
            for (int j = 0; j < 4; ++j) KPs[ty + 16 * i][tx + 16 * j] = s[i][j];
        }
        __syncthreads();  // P tile fully written

        // PV: O[r][d] += sum_c P[r][c] * V[c][d]  (Vst is [d][c])
        for (int c4 = 0; c4 < 64; c4 += 4) {
            float4 a[4], b[4];
            #pragma unroll
            for (int i = 0; i < 4; ++i) a[i] = *(const float4*)&KPs[ty + 16 * i][c4];
            #pragma unroll
            for (int j = 0; j < 4; ++j) b[j] = *(const float4*)&Vst[tx + 16 * j][c4];
            #pragma unroll
            for (int i = 0; i < 4; ++i)
                #pragma unroll
                for (int j = 0; j < 4; ++j)
                    O[i][j] += a[i].x * b[j].x + a[i].y * b[j].y +
                               a[i].z * b[j].z + a[i].w * b[j].w;
        }
    }

    // Normalize and store ctx in [B, S, D] layout (merged heads).
    const int b_ = bh >> 3, h_ = bh & 7;
    #pragma unroll
    for (int i = 0; i < 4; ++i) {
        int qrow = q0 + ty + 16 * i;
        float inv = 1.f / l_i[i];
        #pragma unroll
        for (int j = 0; j < 4; ++j) {
            int c = tx + 16 * j;
            ctx[((size_t)(b_ * SEQ + qrow)) * DMODEL + h_ * HDIM + c] = O[i][j] * inv;
        }
    }
}

// ---------------------------------------------------------------------------
// Kernel 3: output projection. out[m,n] = ctx[m,:] @ Wo[:,n] + bo[n].
// Same GEMM structure as kernel 1, plain row-major store.
// ---------------------------------------------------------------------------
__global__ __launch_bounds__(256) void out_proj_kernel(
    const float* __restrict__ Actx, const float* __restrict__ Wo,
    const float* __restrict__ bo, float* __restrict__ out)
{
    __shared__ float As[64][20];
    __shared__ float Wst[64][20];

    const int tid = threadIdx.x;
    const int tx = tid & 15, ty = tid >> 4;
    const int m0 = blockIdx.y * 64, n0 = blockIdx.x * 64;

    float acc[4][4] = {};

    for (int k0 = 0; k0 < DMODEL; k0 += 16) {
        {
            int mm = tid >> 2, kk = (tid & 3) * 4;
            float4 av = *(const float4*)&Actx[(size_t)(m0 + mm) * DMODEL + k0 + kk];
            *(float4*)&As[mm][kk] = av;
        }
        {
            int c = tid & 63;
            int rbase = tid >> 6;
            #pragma unroll
            for (int p = 0; p < 4; ++p) {
                int r = rbase + 4 * p;
                Wst[c][r] = Wo[(size_t)(k0 + r) * DMODEL + n0 + c];
            }
        }
        __syncthreads();
        for (int k4 = 0; k4 < 16; k4 += 4) {
            float4 a[4], b[4];
            #pragma unroll
            for (int i = 0; i < 4; ++i) a[i] = *(const float4*)&As[ty + 16 * i][k4];
            #pragma unroll
            for (int j = 0; j < 4; ++j) b[j] = *(const float4*)&Wst[tx + 16 * j][k4];
            #pragma unroll
            for (int i = 0; i < 4; ++i)
                #pragma unroll
                for (int j = 0; j < 4; ++j)
                    acc[i][j] += a[i].x * b[j].x + a[i].y * b[j].y +
                                 a[i].z * b[j].z + a[i].w * b[j].w;
        }
        __syncthreads();
    }

    #pragma unroll
    for (int i = 0; i < 4; ++i) {
        int m = m0 + ty + 16 * i;
        #pragma unroll
        for (int j = 0; j < 4; ++j) {
            int n = n0 + tx + 16 * j;
            out[(size_t)m * DMODEL + n] = acc[i][j] + bo[n];
        }
    }
}

// ---------------------------------------------------------------------------
extern "C" void kernel_launch(void* const* d_in, const int* in_sizes, int n_in,
                              void* d_out, int out_size, void* d_ws, size_t ws_size,
                              hipStream_t stream)
{
    const float* qin = (const float*)d_in[0];
    const float* kin = (const float*)d_in[1];
    const float* vin = (const float*)d_in[2];
    const float* Wq  = (const float*)d_in[3];
    const float* bq  = (const float*)d_in[4];
    const float* Wk  = (const float*)d_in[5];
    const float* bk  = (const float*)d_in[6];
    const float* Wv  = (const float*)d_in[7];
    const float* bv  = (const float*)d_in[8];
    const float* Wo  = (const float*)d_in[9];
    const float* bo  = (const float*)d_in[10];

    float* ws  = (float*)d_ws;      // Q | K | V | ctx, each QSIZE floats (33.5 MB)
    float* out = (float*)d_out;

    dim3 gp(DMODEL / 64, MTOT / 64, 3);
    qkv_proj_kernel<<<gp, 256, 0, stream>>>(qin, kin, vin, Wq, bq, Wk, bk, Wv, bv, ws);

    dim3 ga(BATCH * NH, SEQ / 64);
    attn_kernel<<<ga, 256, 0, stream>>>(ws, ws + 3 * (size_t)QSIZE);

    dim3 go(DMODEL / 64, MTOT / 64);
    out_proj_kernel<<<go, 256, 0, stream>>>(ws + 3 * (size_t)QSIZE, Wo, bo, out);
}

// Round 2
// 207.954 us; speedup vs baseline: 2.8082x; 2.8082x over previous
//
#include <hip/hip_runtime.h>
#include <math.h>

#define BATCH 2
#define SEQ 2048
#define DMODEL 512
#define NH 8
#define HDIM 64
#define MTOT (BATCH * SEQ)              // 4096
#define QSIZE (BATCH * NH * SEQ * HDIM) // 2097152 elems per tensor

// MFMA fragment types (per guide §3: short8 = 8 bf16 = 4 VGPRs)
typedef __attribute__((ext_vector_type(8))) short bf16x8;
typedef __attribute__((ext_vector_type(4))) float f32x4;

// fp32 -> bf16 RNE
__device__ inline unsigned short f2bf(float f) {
    union { float f; unsigned u; } v; v.f = f;
    unsigned u = v.u;
    u += 0x7fffu + ((u >> 16) & 1u);
    return (unsigned short)(u >> 16);
}
__device__ inline unsigned pack2(float lo, float hi) {
    return (unsigned)f2bf(lo) | ((unsigned)f2bf(hi) << 16);
}

// LDS tile stride: 72 elems = 144 B. Multiple of 16 B (ds_read_b128 align),
// not multiple of 128 B (avoids all-rows-same-bank on B-frag reads).
#define LSTR 72

// ---------------------------------------------------------------------------
// Kernel 1: fused QKV projection, bf16 MFMA.
// C[m,n] = A[m,:]@W[:,n] + b[n]; Q additionally scaled by 0.125.
// Output bf16 in [B,H,S,HD]. 64x64 tile, ktile 64, 4 waves (16 rows each).
// A-frag: A[m=lane&15][k=quad*8+j] row-major LDS.
// B-frag: B[k][n]: n=lane&15, k=quad*8+j -> LDS holds Wt[n][k] (transposed).
// C/D:    col=lane&15, row=quad*4+reg.
// ---------------------------------------------------------------------------
__global__ __launch_bounds__(256) void qkv_mfma_kernel(
    const float* __restrict__ qin, const float* __restrict__ kin,
    const float* __restrict__ vin,
    const float* __restrict__ Wq, const float* __restrict__ bq,
    const float* __restrict__ Wk, const float* __restrict__ bk,
    const float* __restrict__ Wv, const float* __restrict__ bv,
    unsigned short* __restrict__ ws)
{
    const int which = blockIdx.z;
    const float* A    = (which == 0) ? qin : (which == 1) ? kin : vin;
    const float* W    = (which == 0) ? Wq  : (which == 1) ? Wk  : Wv;
    const float* bias = (which == 0) ? bq  : (which == 1) ? bk  : bv;
    unsigned short* out = ws + (size_t)which * QSIZE;

    __shared__ __align__(16) short As[64][LSTR];  // A tile [m][k] bf16
    __shared__ __align__(16) short Bs[64][LSTR];  // Wt tile [n][k] bf16

    const int tid = threadIdx.x;
    const int lane = tid & 63, wave = tid >> 6;
    const int lrow = lane & 15, quad = lane >> 4;
    const int m0 = blockIdx.y * 64, n0 = blockIdx.x * 64;

    // staging indices
    const int ar = tid >> 2, ac = (tid & 3) * 16;      // A: row, 16 cols
    const int bp = tid >> 3, bc = tid & 7;             // W: k-row pair, 8 n's

    f32x4 acc[4];
    #pragma unroll
    for (int n = 0; n < 4; ++n) acc[n] = f32x4{0.f, 0.f, 0.f, 0.f};

    for (int k0 = 0; k0 < DMODEL; k0 += 64) {
        __syncthreads();
        // ---- stage A: fp32 load, cvt, row-major bf16 ----
        {
            const float* ap = A + (size_t)(m0 + ar) * DMODEL + k0 + ac;
            float4 a0 = *(const float4*)(ap + 0);
            float4 a1 = *(const float4*)(ap + 4);
            float4 a2 = *(const float4*)(ap + 8);
            float4 a3 = *(const float4*)(ap + 12);
            uint4 h0, h1;
            h0.x = pack2(a0.x, a0.y); h0.y = pack2(a0.z, a0.w);
            h0.z = pack2(a1.x, a1.y); h0.w = pack2(a1.z, a1.w);
            h1.x = pack2(a2.x, a2.y); h1.y = pack2(a2.z, a2.w);
            h1.z = pack2(a3.x, a3.y); h1.w = pack2(a3.z, a3.w);
            *(uint4*)&As[ar][ac]     = h0;
            *(uint4*)&As[ar][ac + 8] = h1;
        }
        // ---- stage W transposed: Bs[n][k] = W[k][n] bf16 ----
        {
            const float* wp0 = W + (size_t)(k0 + 2 * bp) * DMODEL + n0 + 8 * bc;
            const float* wp1 = wp0 + DMODEL;
            float4 w00 = *(const float4*)(wp0 + 0);
            float4 w01 = *(const float4*)(wp0 + 4);
            float4 w10 = *(const float4*)(wp1 + 0);
            float4 w11 = *(const float4*)(wp1 + 4);
            *(unsigned*)&Bs[8 * bc + 0][2 * bp] = pack2(w00.x, w10.x);
            *(unsigned*)&Bs[8 * bc + 1][2 * bp] = pack2(w00.y, w10.y);
            *(unsigned*)&Bs[8 * bc + 2][2 * bp] = pack2(w00.z, w10.z);
            *(unsigned*)&Bs[8 * bc + 3][2 * bp] = pack2(w00.w, w10.w);
            *(unsigned*)&Bs[8 * bc + 4][2 * bp] = pack2(w01.x, w11.x);
            *(unsigned*)&Bs[8 * bc + 5][2 * bp] = pack2(w01.y, w11.y);
            *(unsigned*)&Bs[8 * bc + 6][2 * bp] = pack2(w01.z, w11.z);
            *(unsigned*)&Bs[8 * bc + 7][2 * bp] = pack2(w01.w, w11.w);
        }
        __syncthreads();
        // ---- MFMA: 2 k-steps x 4 n-tiles ----
        bf16x8 af0 = *(const bf16x8*)&As[wave * 16 + lrow][quad * 8];
        bf16x8 af1 = *(const bf16x8*)&As[wave * 16 + lrow][32 + quad * 8];
        #pragma unroll
        for (int n = 0; n < 4; ++n) {
            bf16x8 b0 = *(const bf16x8*)&Bs[n * 16 + lrow][quad * 8];
            bf16x8 b1 = *(const bf16x8*)&Bs[n * 16 + lrow][32 + quad * 8];
            acc[n] = __builtin_amdgcn_mfma_f32_16x16x32_bf16(af0, b0, acc[n], 0, 0, 0);
            acc[n] = __builtin_amdgcn_mfma_f32_16x16x32_bf16(af1, b1, acc[n], 0, 0, 0);
        }
    }

    // ---- epilogue: bias (+0.125 scale for Q), bf16 store [B,H,S,HD] ----
    const float scale = (which == 0) ? 0.125f : 1.0f;
    #pragma unroll
    for (int n = 0; n < 4; ++n) {
        const int col = n0 + n * 16 + lrow;          // n in [0,512)
        const int h_ = col >> 6, hd_ = col & 63;
        const float bv_ = bias[col];
        #pragma unroll
        for (int r = 0; r < 4; ++r) {
            const int m = m0 + wave * 16 + quad * 4 + r;
            const int b_ = m >> 11, s_ = m & (SEQ - 1);
            const float v = (acc[n][r] + bv_) * scale;
            out[((size_t)((b_ * NH + h_) * SEQ + s_)) * HDIM + hd_] = f2bf(v);
        }
    }
}

// ---------------------------------------------------------------------------
// Kernel 2: bf16 MFMA flash attention. grid=(B*H=16, S/64=32), 256 thr.
// Q-frags in registers (Q pre-scaled). Per ktile: stage K row-major +
// V transposed in LDS, QK^T MFMA, per-wave online softmax (wave owns 16 q
// rows -> P rows private to wave, no barrier for P), PV MFMA.
// ctx written bf16 [B,S,D].
// ---------------------------------------------------------------------------
__global__ __launch_bounds__(256) void attn_mfma_kernel(
    const unsigned short* __restrict__ ws, unsigned short* __restrict__ ctx)
{
    const unsigned short* Q = ws;
    const unsigned short* K = ws + (size_t)QSIZE;
    const unsigned short* V = ws + 2 * (size_t)QSIZE;

    __shared__ __align__(16) short Ks[64][LSTR];  // K[key][hd] bf16
    __shared__ __align__(16) short Vt[64][LSTR];  // V^T[hd][key] bf16
    __shared__ __align__(16) short Ps[64][LSTR];  // P[q][key] bf16 (per-wave rows)

    const int bh = blockIdx.x;
    const int q0 = blockIdx.y * 64;
    const int tid = threadIdx.x;
    const int lane = tid & 63, wave = tid >> 6;
    const int lrow = lane & 15, quad = lane >> 4;
    const size_t base = (size_t)bh * SEQ * HDIM;

    // Q fragments (A-layout): rows wave*16+lrow, k = s*32 + quad*8 + j
    const unsigned short* qrow = Q + base + (size_t)(q0 + wave * 16 + lrow) * HDIM;
    const bf16x8 qa0 = *(const bf16x8*)(qrow + quad * 8);
    const bf16x8 qa1 = *(const bf16x8*)(qrow + 32 + quad * 8);

    float m_i[4], l_i[4];
    f32x4 oacc[4];
    #pragma unroll
    for (int r = 0; r < 4; ++r) { m_i[r] = -1e30f; l_i[r] = 0.f; }
    #pragma unroll
    for (int n = 0; n < 4; ++n) oacc[n] = f32x4{0.f, 0.f, 0.f, 0.f};

    // staging indices
    const int kr = tid >> 2, kc = (tid & 3) * 16;  // K: row, 16 cols
    const int vp = tid >> 3, vc = tid & 7;         // V: key-row pair, 8 hd's

    for (int kt = 0; kt < SEQ; kt += 64) {
        __syncthreads();  // prior QK/PV reads of Ks/Vt complete
        {   // stage K tile row-major (bf16 global -> LDS, 32B/thread)
            const unsigned short* kp = K + base + (size_t)(kt + kr) * HDIM + kc;
            uint4 k0 = *(const uint4*)kp;
            uint4 k1 = *(const uint4*)(kp + 8);
            *(uint4*)&Ks[kr][kc]     = k0;
            *(uint4*)&Ks[kr][kc + 8] = k1;
        }
        {   // stage V transposed: Vt[hd][key]; pack 2 keys per dword
            const unsigned short* vptr0 = V + base + (size_t)(kt + 2 * vp) * HDIM + 8 * vc;
            union { uint4 v; unsigned short s[8]; } r0, r1;
            r0.v = *(const uint4*)vptr0;
            r1.v = *(const uint4*)(vptr0 + HDIM);
            #pragma unroll
            for (int i = 0; i < 8; ++i) {
                *(unsigned*)&Vt[8 * vc + i][2 * vp] =
                    (unsigned)r0.s[i] | ((unsigned)r1.s[i] << 16);
            }
        }
        __syncthreads();

        // ---- QK^T: S[16q x 64k] per wave ----
        f32x4 s[4];
        #pragma unroll
        for (int n = 0; n < 4; ++n) {
            bf16x8 kb0 = *(const bf16x8*)&Ks[n * 16 + lrow][quad * 8];
            bf16x8 kb1 = *(const bf16x8*)&Ks[n * 16 + lrow][32 + quad * 8];
            f32x4 z = f32x4{0.f, 0.f, 0.f, 0.f};
            z = __builtin_amdgcn_mfma_f32_16x16x32_bf16(qa0, kb0, z, 0, 0, 0);
            z = __builtin_amdgcn_mfma_f32_16x16x32_bf16(qa1, kb1, z, 0, 0, 0);
            s[n] = z;
        }

        // ---- online softmax; lane owns rows quad*4+r, cols n*16+lrow ----
        #pragma unroll
        for (int r = 0; r < 4; ++r) {
            float rmax = fmaxf(fmaxf(s[0][r], s[1][r]), fmaxf(s[2][r], s[3][r]));
            #pragma unroll
            for (int off = 1; off < 16; off <<= 1)
                rmax = fmaxf(rmax, __shfl_xor(rmax, off));
            const float mnew = fmaxf(m_i[r], rmax);
            const float alpha = __expf(m_i[r] - mnew);
            float rsum = 0.f;
            float p[4];
            #pragma unroll
            for (int n = 0; n < 4; ++n) {
                p[n] = __expf(s[n][r] - mnew);
                rsum += p[n];
            }
            #pragma unroll
            for (int off = 1; off < 16; off <<= 1)
                rsum += __shfl_xor(rsum, off);
            l_i[r] = l_i[r] * alpha + rsum;
            m_i[r] = mnew;
            #pragma unroll
            for (int n = 0; n < 4; ++n) oacc[n][r] *= alpha;
            const int prow = wave * 16 + quad * 4 + r;
            #pragma unroll
            for (int n = 0; n < 4; ++n)
                Ps[prow][n * 16 + lrow] = (short)f2bf(p[n]);
        }
        // P rows are wave-private: no __syncthreads needed (lgkmcnt only).

        // ---- PV: O[16q x 64d] += P @ V ----
        bf16x8 pa0 = *(const bf16x8*)&Ps[wave * 16 + lrow][quad * 8];
        bf16x8 pa1 = *(const bf16x8*)&Ps[wave * 16 + lrow][32 + quad * 8];
        #pragma unroll
        for (int n = 0; n < 4; ++n) {
            bf16x8 vb0 = *(const bf16x8*)&Vt[n * 16 + lrow][quad * 8];
            bf16x8 vb1 = *(const bf16x8*)&Vt[n * 16 + lrow][32 + quad * 8];
            oacc[n] = __builtin_amdgcn_mfma_f32_16x16x32_bf16(pa0, vb0, oacc[n], 0, 0, 0);
            oacc[n] = __builtin_amdgcn_mfma_f32_16x16x32_bf16(pa1, vb1, oacc[n], 0, 0, 0);
        }
    }

    // ---- epilogue: normalize, bf16 ctx [B,S,D] ----
    const int b_ = bh >> 3, h_ = bh & 7;
    #pragma unroll
    for (int r = 0; r < 4; ++r) {
        const int row = q0 + wave * 16 + quad * 4 + r;
        const float inv = 1.f / l_i[r];
        #pragma unroll
        for (int n = 0; n < 4; ++n) {
            const int col = h_ * HDIM + n * 16 + lrow;
            ctx[((size_t)(b_ * SEQ + row)) * DMODEL + col] = f2bf(oacc[n][r] * inv);
        }
    }
}

// ---------------------------------------------------------------------------
// Kernel 3: output projection, bf16 MFMA. A = ctx bf16 [4096,512],
// B = Wo fp32 (transpose-staged to bf16), fp32 epilogue + bias to d_out.
// ---------------------------------------------------------------------------
__global__ __launch_bounds__(256) void out_proj_mfma_kernel(
    const unsigned short* __restrict__ ctx, const float* __restrict__ Wo,
    const float* __restrict__ bo, float* __restrict__ out)
{
    __shared__ __align__(16) short As[64][LSTR];
    __shared__ __align__(16) short Bs[64][LSTR];

    const int tid = threadIdx.x;
    const int lane = tid & 63, wave = tid >> 6;
    const int lrow = lane & 15, quad = lane >> 4;
    const int m0 = blockIdx.y * 64, n0 = blockIdx.x * 64;

    const int ar = tid >> 2, ac = (tid & 3) * 16;
    const int bp = tid >> 3, bc = tid & 7;

    f32x4 acc[4];
    #pragma unroll
    for (int n = 0; n < 4; ++n) acc[n] = f32x4{0.f, 0.f, 0.f, 0.f};

    for (int k0 = 0; k0 < DMODEL; k0 += 64) {
        __syncthreads();
        {   // stage A (already bf16): straight copy
            const unsigned short* ap = ctx + (size_t)(m0 + ar) * DMODEL + k0 + ac;
            uint4 a0 = *(const uint4*)ap;
            uint4 a1 = *(const uint4*)(ap + 8);
            *(uint4*)&As[ar][ac]     = a0;
            *(uint4*)&As[ar][ac + 8] = a1;
        }
        {   // stage Wo transposed bf16
            const float* wp0 = Wo + (size_t)(k0 + 2 * bp) * DMODEL + n0 + 8 * bc;
            const float* wp1 = wp0 + DMODEL;
            float4 w00 = *(const float4*)(wp0 + 0);
            float4 w01 = *(const float4*)(wp0 + 4);
            float4 w10 = *(const float4*)(wp1 + 0);
            float4 w11 = *(const float4*)(wp1 + 4);
            *(unsigned*)&Bs[8 * bc + 0][2 * bp] = pack2(w00.x, w10.x);
            *(unsigned*)&Bs[8 * bc + 1][2 * bp] = pack2(w00.y, w10.y);
            *(unsigned*)&Bs[8 * bc + 2][2 * bp] = pack2(w00.z, w10.z);
            *(unsigned*)&Bs[8 * bc + 3][2 * bp] = pack2(w00.w, w10.w);
            *(unsigned*)&Bs[8 * bc + 4][2 * bp] = pack2(w01.x, w11.x);
            *(unsigned*)&Bs[8 * bc + 5][2 * bp] = pack2(w01.y, w11.y);
            *(unsigned*)&Bs[8 * bc + 6][2 * bp] = pack2(w01.z, w11.z);
            *(unsigned*)&Bs[8 * bc + 7][2 * bp] = pack2(w01.w, w11.w);
        }
        __syncthreads();
        bf16x8 af0 = *(const bf16x8*)&As[wave * 16 + lrow][quad * 8];
        bf16x8 af1 = *(const bf16x8*)&As[wave * 16 + lrow][32 + quad * 8];
        #pragma unroll
        for (int n = 0; n < 4; ++n) {
            bf16x8 b0 = *(const bf16x8*)&Bs[n * 16 + lrow][quad * 8];
            bf16x8 b1 = *(const bf16x8*)&Bs[n * 16 + lrow][32 + quad * 8];
            acc[n] = __builtin_amdgcn_mfma_f32_16x16x32_bf16(af0, b0, acc[n], 0, 0, 0);
            acc[n] = __builtin_amdgcn_mfma_f32_16x16x32_bf16(af1, b1, acc[n], 0, 0, 0);
        }
    }

    #pragma unroll
    for (int n = 0; n < 4; ++n) {
        const int col = n0 + n * 16 + lrow;
        const float bv_ = bo[col];
        #pragma unroll
        for (int r = 0; r < 4; ++r) {
            const int m = m0 + wave * 16 + quad * 4 + r;
            out[(size_t)m * DMODEL + col] = acc[n][r] + bv_;
        }
    }
}

// ---------------------------------------------------------------------------
extern "C" void kernel_launch(void* const* d_in, const int* in_sizes, int n_in,
                              void* d_out, int out_size, void* d_ws, size_t ws_size,
                              hipStream_t stream)
{
    const float* qin = (const float*)d_in[0];
    const float* kin = (const float*)d_in[1];
    const float* vin = (const float*)d_in[2];
    const float* Wq  = (const float*)d_in[3];
    const float* bq  = (const float*)d_in[4];
    const float* Wk  = (const float*)d_in[5];
    const float* bk  = (const float*)d_in[6];
    const float* Wv  = (const float*)d_in[7];
    const float* bv  = (const float*)d_in[8];
    const float* Wo  = (const float*)d_in[9];
    const float* bo  = (const float*)d_in[10];

    unsigned short* ws = (unsigned short*)d_ws;  // Q|K|V|ctx bf16, 16.8 MB
    float* out = (float*)d_out;

    dim3 gp(DMODEL / 64, MTOT / 64, 3);
    qkv_mfma_kernel<<<gp, 256, 0, stream>>>(qin, kin, vin, Wq, bq, Wk, bk, Wv, bv, ws);

    dim3 ga(BATCH * NH, SEQ / 64);
    attn_mfma_kernel<<<ga, 256, 0, stream>>>(ws, ws + 3 * (size_t)QSIZE);

    dim3 go(DMODEL / 64, MTOT / 64);
    out_proj_mfma_kernel<<<go, 256, 0, stream>>>(ws + 3 * (size_t)QSIZE, Wo, bo, out);
}

// Round 3
// 187.416 us; speedup vs baseline: 3.1159x; 1.1096x over previous
//
#include <hip/hip_runtime.h>
#include <math.h>

#define BATCH 2
#define SEQ 2048
#define DMODEL 512
#define NH 8
#define HDIM 64
#define MTOT (BATCH * SEQ)              // 4096
#define QSIZE (BATCH * NH * SEQ * HDIM) // 2097152 elems per tensor
#define WSIZE (DMODEL * DMODEL)         // 262144 elems per weight

typedef __attribute__((ext_vector_type(8))) short bf16x8;
typedef __attribute__((ext_vector_type(4))) float f32x4;

__device__ inline unsigned short f2bf(float f) {
    union { float f; unsigned u; } v; v.f = f;
    unsigned u = v.u;
    u += 0x7fffu + ((u >> 16) & 1u);
    return (unsigned short)(u >> 16);
}
__device__ inline unsigned pack2(float lo, float hi) {
    return (unsigned)f2bf(lo) | ((unsigned)f2bf(hi) << 16);
}

// LDS row stride: 72 elems = 144 B (16B-aligned, 36 dwords -> rows shift
// banks by 4, avoiding same-bank columns).
#define LSTR 72

// ws layout (bf16 elems): Q | K | V(transposed per head) | ctx | Wt q,k,v,o
#define WS_Q   0
#define WS_K   ((size_t)QSIZE)
#define WS_V   (2 * (size_t)QSIZE)
#define WS_CTX (3 * (size_t)QSIZE)
#define WS_WT  (4 * (size_t)QSIZE)

// ---------------------------------------------------------------------------
// Kernel 0: transpose + bf16-convert the 4 weight matrices.
// W[k][n] fp32 -> Wt[n][k] bf16. grid (16,16,4), 256 thr, 32x32 tiles.
// ---------------------------------------------------------------------------
__global__ __launch_bounds__(256) void wt_prep_kernel(
    const float* __restrict__ Wq, const float* __restrict__ Wk,
    const float* __restrict__ Wv, const float* __restrict__ Wo,
    unsigned short* __restrict__ wt)
{
    const int z = blockIdx.z;
    const float* W = (z == 0) ? Wq : (z == 1) ? Wk : (z == 2) ? Wv : Wo;
    unsigned short* Wt = wt + (size_t)z * WSIZE;

    __shared__ float T[32][33];
    const int tid = threadIdx.x;
    const int k0 = blockIdx.x * 32, n0 = blockIdx.y * 32;

    {   // load 32x32 fp32 tile, coalesced
        int r = tid >> 3, c = (tid & 7) * 4;
        float4 v = *(const float4*)&W[(size_t)(k0 + r) * DMODEL + n0 + c];
        T[r][c + 0] = v.x; T[r][c + 1] = v.y; T[r][c + 2] = v.z; T[r][c + 3] = v.w;
    }
    __syncthreads();
    {   // write transposed bf16: Wt[n][k]
        int n = tid >> 3, c = (tid & 7) * 4;   // c = k offset
        uint2 o;
        o.x = pack2(T[c + 0][n], T[c + 1][n]);
        o.y = pack2(T[c + 2][n], T[c + 3][n]);
        *(uint2*)&Wt[(size_t)(n0 + n) * DMODEL + k0 + c] = o;
    }
}

// ---------------------------------------------------------------------------
// Kernel 1: fused QKV projection, bf16 MFMA, 128x128 tiles.
// grid (N/128=4, M/128=32, 3). 4 waves; wave owns 32 rows x 128 cols.
// Q scaled by 0.125. Q,K stored [B,H,S,HD]; V stored [B,H,HD,S] (transposed).
// ---------------------------------------------------------------------------
__global__ __launch_bounds__(256) void qkv_mfma_kernel(
    const float* __restrict__ qin, const float* __restrict__ kin,
    const float* __restrict__ vin,
    const float* __restrict__ bq, const float* __restrict__ bk,
    const float* __restrict__ bv,
    unsigned short* __restrict__ ws)
{
    const int which = blockIdx.z;
    const float* A    = (which == 0) ? qin : (which == 1) ? kin : vin;
    const float* bias = (which == 0) ? bq  : (which == 1) ? bk  : bv;
    const unsigned short* Wt = ws + WS_WT + (size_t)which * WSIZE;
    unsigned short* out = ws + (size_t)which * QSIZE;

    __shared__ __align__(16) short As[128][LSTR];
    __shared__ __align__(16) short Bs[128][LSTR];

    const int tid = threadIdx.x;
    const int lane = tid & 63, wave = tid >> 6;
    const int lrow = lane & 15, quad = lane >> 4;
    const int m0 = blockIdx.y * 128, n0 = blockIdx.x * 128;

    const int sr = tid >> 1;             // staging row 0..127
    const int sh = (tid & 1) * 32;       // col half (elems)

    f32x4 acc[2][8];
    #pragma unroll
    for (int i = 0; i < 2; ++i)
        #pragma unroll
        for (int n = 0; n < 8; ++n) acc[i][n] = f32x4{0.f, 0.f, 0.f, 0.f};

    for (int k0 = 0; k0 < DMODEL; k0 += 64) {
        __syncthreads();
        {   // stage A: 32 fp32 -> bf16 per thread
            const float* ap = A + (size_t)(m0 + sr) * DMODEL + k0 + sh;
            float4 a0 = *(const float4*)(ap + 0),  a1 = *(const float4*)(ap + 4);
            float4 a2 = *(const float4*)(ap + 8),  a3 = *(const float4*)(ap + 12);
            float4 a4 = *(const float4*)(ap + 16), a5 = *(const float4*)(ap + 20);
            float4 a6 = *(const float4*)(ap + 24), a7 = *(const float4*)(ap + 28);
            uint4 h0 = {pack2(a0.x,a0.y), pack2(a0.z,a0.w), pack2(a1.x,a1.y), pack2(a1.z,a1.w)};
            uint4 h1 = {pack2(a2.x,a2.y), pack2(a2.z,a2.w), pack2(a3.x,a3.y), pack2(a3.z,a3.w)};
            uint4 h2 = {pack2(a4.x,a4.y), pack2(a4.z,a4.w), pack2(a5.x,a5.y), pack2(a5.z,a5.w)};
            uint4 h3 = {pack2(a6.x,a6.y), pack2(a6.z,a6.w), pack2(a7.x,a7.y), pack2(a7.z,a7.w)};
            *(uint4*)&As[sr][sh + 0]  = h0;
            *(uint4*)&As[sr][sh + 8]  = h1;
            *(uint4*)&As[sr][sh + 16] = h2;
            *(uint4*)&As[sr][sh + 24] = h3;
        }
        {   // stage B: straight bf16 copy from Wt[n][k]
            const unsigned short* wp = Wt + (size_t)(n0 + sr) * DMODEL + k0 + sh;
            uint4 b0 = *(const uint4*)(wp + 0),  b1 = *(const uint4*)(wp + 8);
            uint4 b2 = *(const uint4*)(wp + 16), b3 = *(const uint4*)(wp + 24);
            *(uint4*)&Bs[sr][sh + 0]  = b0;
            *(uint4*)&Bs[sr][sh + 8]  = b1;
            *(uint4*)&Bs[sr][sh + 16] = b2;
            *(uint4*)&Bs[sr][sh + 24] = b3;
        }
        __syncthreads();
        #pragma unroll
        for (int s = 0; s < 2; ++s) {
            bf16x8 af[2];
            #pragma unroll
            for (int i = 0; i < 2; ++i)
                af[i] = *(const bf16x8*)&As[wave * 32 + i * 16 + lrow][s * 32 + quad * 8];
            #pragma unroll
            for (int n = 0; n < 8; ++n) {
                bf16x8 bf = *(const bf16x8*)&Bs[n * 16 + lrow][s * 32 + quad * 8];
                acc[0][n] = __builtin_amdgcn_mfma_f32_16x16x32_bf16(af[0], bf, acc[0][n], 0, 0, 0);
                acc[1][n] = __builtin_amdgcn_mfma_f32_16x16x32_bf16(af[1], bf, acc[1][n], 0, 0, 0);
            }
        }
    }

    if (which < 2) {
        // Q/K: [B,H,S,HD], scalar bf16 stores (16-lane 32B runs)
        const float scale = (which == 0) ? 0.125f : 1.0f;
        #pragma unroll
        for (int n = 0; n < 8; ++n) {
            const int col = n0 + n * 16 + lrow;
            const int h_ = col >> 6, hd_ = col & 63;
            const float bv_ = bias[col];
            #pragma unroll
            for (int i = 0; i < 2; ++i) {
                #pragma unroll
                for (int r = 0; r < 4; ++r) {
                    const int m = m0 + wave * 32 + i * 16 + quad * 4 + r;
                    const int b_ = m >> 11, s_ = m & (SEQ - 1);
                    const float v = (acc[i][n][r] + bv_) * scale;
                    out[((size_t)((b_ * NH + h_) * SEQ + s_)) * HDIM + hd_] = f2bf(v);
                }
            }
        }
    } else {
        // V: [B,H,HD,S]; 4 consecutive s per lane -> uint2 stores
        #pragma unroll
        for (int n = 0; n < 8; ++n) {
            const int col = n0 + n * 16 + lrow;
            const int h_ = col >> 6, hd_ = col & 63;
            const float bv_ = bias[col];
            #pragma unroll
            for (int i = 0; i < 2; ++i) {
                const int m = m0 + wave * 32 + i * 16 + quad * 4;  // 4 consecutive s
                const int b_ = m >> 11, s_ = m & (SEQ - 1);
                uint2 o;
                o.x = pack2(acc[i][n][0] + bv_, acc[i][n][1] + bv_);
                o.y = pack2(acc[i][n][2] + bv_, acc[i][n][3] + bv_);
                *(uint2*)&out[((size_t)((b_ * NH + h_) * HDIM + hd_)) * SEQ + s_] = o;
            }
        }
    }
}

// ---------------------------------------------------------------------------
// Kernel 2: bf16 MFMA flash attention. grid=(B*H=16, S/64=32), 256 thr.
// V is pre-transposed in global -> Vt staging is a straight copy.
// ---------------------------------------------------------------------------
__global__ __launch_bounds__(256) void attn_mfma_kernel(
    const unsigned short* __restrict__ ws, unsigned short* __restrict__ ctx)
{
    const unsigned short* Q = ws + WS_Q;
    const unsigned short* K = ws + WS_K;
    const unsigned short* V = ws + WS_V;   // [B,H,HD,S]

    __shared__ __align__(16) short Ks[64][LSTR];  // K[key][hd]
    __shared__ __align__(16) short Vt[64][LSTR];  // V^T[hd][key]
    __shared__ __align__(16) short Ps[64][LSTR];  // P[q][key]

    const int bh = blockIdx.x;
    const int q0 = blockIdx.y * 64;
    const int tid = threadIdx.x;
    const int lane = tid & 63, wave = tid >> 6;
    const int lrow = lane & 15, quad = lane >> 4;
    const size_t base = (size_t)bh * SEQ * HDIM;

    const unsigned short* qrow = Q + base + (size_t)(q0 + wave * 16 + lrow) * HDIM;
    const bf16x8 qa0 = *(const bf16x8*)(qrow + quad * 8);
    const bf16x8 qa1 = *(const bf16x8*)(qrow + 32 + quad * 8);

    float m_i[4], l_i[4];
    f32x4 oacc[4];
    #pragma unroll
    for (int r = 0; r < 4; ++r) { m_i[r] = -1e30f; l_i[r] = 0.f; }
    #pragma unroll
    for (int n = 0; n < 4; ++n) oacc[n] = f32x4{0.f, 0.f, 0.f, 0.f};

    const int kr = tid >> 2, kc = (tid & 3) * 16;  // K: row, 16 hd
    const int vr = tid >> 2, vq = (tid & 3) * 16;  // Vt: hd row, 16 keys

    for (int kt = 0; kt < SEQ; kt += 64) {
        __syncthreads();
        {   // stage K row-major
            const unsigned short* kp = K + base + (size_t)(kt + kr) * HDIM + kc;
            uint4 k0 = *(const uint4*)kp;
            uint4 k1 = *(const uint4*)(kp + 8);
            *(uint4*)&Ks[kr][kc]     = k0;
            *(uint4*)&Ks[kr][kc + 8] = k1;
        }
        {   // stage Vt: straight copy from transposed global V
            const unsigned short* vp = V + base + (size_t)vr * SEQ + kt + vq;
            uint4 v0 = *(const uint4*)vp;
            uint4 v1 = *(const uint4*)(vp + 8);
            *(uint4*)&Vt[vr][vq]     = v0;
            *(uint4*)&Vt[vr][vq + 8] = v1;
        }
        __syncthreads();

        // QK^T
        f32x4 s[4];
        #pragma unroll
        for (int n = 0; n < 4; ++n) {
            bf16x8 kb0 = *(const bf16x8*)&Ks[n * 16 + lrow][quad * 8];
            bf16x8 kb1 = *(const bf16x8*)&Ks[n * 16 + lrow][32 + quad * 8];
            f32x4 z = f32x4{0.f, 0.f, 0.f, 0.f};
            z = __builtin_amdgcn_mfma_f32_16x16x32_bf16(qa0, kb0, z, 0, 0, 0);
            z = __builtin_amdgcn_mfma_f32_16x16x32_bf16(qa1, kb1, z, 0, 0, 0);
            s[n] = z;
        }

        // online softmax (lane owns rows quad*4+r, cols n*16+lrow)
        #pragma unroll
        for (int r = 0; r < 4; ++r) {
            float rmax = fmaxf(fmaxf(s[0][r], s[1][r]), fmaxf(s[2][r], s[3][r]));
            #pragma unroll
            for (int off = 1; off < 16; off <<= 1)
                rmax = fmaxf(rmax, __shfl_xor(rmax, off));
            const float mnew = fmaxf(m_i[r], rmax);
            const float alpha = __expf(m_i[r] - mnew);
            float rsum = 0.f;
            float p[4];
            #pragma unroll
            for (int n = 0; n < 4; ++n) {
                p[n] = __expf(s[n][r] - mnew);
                rsum += p[n];
            }
            #pragma unroll
            for (int off = 1; off < 16; off <<= 1)
                rsum += __shfl_xor(rsum, off);
            l_i[r] = l_i[r] * alpha + rsum;
            m_i[r] = mnew;
            #pragma unroll
            for (int n = 0; n < 4; ++n) oacc[n][r] *= alpha;
            const int prow = wave * 16 + quad * 4 + r;
            #pragma unroll
            for (int n = 0; n < 4; ++n)
                Ps[prow][n * 16 + lrow] = (short)f2bf(p[n]);
        }
        // P rows are wave-private: no barrier needed before PV.

        // PV
        bf16x8 pa0 = *(const bf16x8*)&Ps[wave * 16 + lrow][quad * 8];
        bf16x8 pa1 = *(const bf16x8*)&Ps[wave * 16 + lrow][32 + quad * 8];
        #pragma unroll
        for (int n = 0; n < 4; ++n) {
            bf16x8 vb0 = *(const bf16x8*)&Vt[n * 16 + lrow][quad * 8];
            bf16x8 vb1 = *(const bf16x8*)&Vt[n * 16 + lrow][32 + quad * 8];
            oacc[n] = __builtin_amdgcn_mfma_f32_16x16x32_bf16(pa0, vb0, oacc[n], 0, 0, 0);
            oacc[n] = __builtin_amdgcn_mfma_f32_16x16x32_bf16(pa1, vb1, oacc[n], 0, 0, 0);
        }
    }

    const int b_ = bh >> 3, h_ = bh & 7;
    #pragma unroll
    for (int r = 0; r < 4; ++r) {
        const int row = q0 + wave * 16 + quad * 4 + r;
        const float inv = 1.f / l_i[r];
        #pragma unroll
        for (int n = 0; n < 4; ++n) {
            const int col = h_ * HDIM + n * 16 + lrow;
            ctx[((size_t)(b_ * SEQ + row)) * DMODEL + col] = f2bf(oacc[n][r] * inv);
        }
    }
}

// ---------------------------------------------------------------------------
// Kernel 3: output projection, bf16 MFMA, 128x64 tiles.
// grid (N/64=8, M/128=32) = 256 blocks. Wave owns 32 rows x 64 cols.
// ---------------------------------------------------------------------------
__global__ __launch_bounds__(256) void out_proj_mfma_kernel(
    const unsigned short* __restrict__ ws, const float* __restrict__ bo,
    float* __restrict__ out)
{
    const unsigned short* ctx = ws + WS_CTX;
    const unsigned short* Wt  = ws + WS_WT + 3 * (size_t)WSIZE;  // Wo transposed

    __shared__ __align__(16) short As[128][LSTR];
    __shared__ __align__(16) short Bs[64][LSTR];

    const int tid = threadIdx.x;
    const int lane = tid & 63, wave = tid >> 6;
    const int lrow = lane & 15, quad = lane >> 4;
    const int m0 = blockIdx.y * 128, n0 = blockIdx.x * 64;

    const int sr = tid >> 1, sh = (tid & 1) * 32;   // A staging
    const int br = tid >> 2, bqr = (tid & 3) * 16;  // B staging

    f32x4 acc[2][4];
    #pragma unroll
    for (int i = 0; i < 2; ++i)
        #pragma unroll
        for (int n = 0; n < 4; ++n) acc[i][n] = f32x4{0.f, 0.f, 0.f, 0.f};

    for (int k0 = 0; k0 < DMODEL; k0 += 64) {
        __syncthreads();
        {   // stage A (bf16 straight copy)
            const unsigned short* ap = ctx + (size_t)(m0 + sr) * DMODEL + k0 + sh;
            uint4 c0 = *(const uint4*)(ap + 0),  c1 = *(const uint4*)(ap + 8);
            uint4 c2 = *(const uint4*)(ap + 16), c3 = *(const uint4*)(ap + 24);
            *(uint4*)&As[sr][sh + 0]  = c0;
            *(uint4*)&As[sr][sh + 8]  = c1;
            *(uint4*)&As[sr][sh + 16] = c2;
            *(uint4*)&As[sr][sh + 24] = c3;
        }
        {   // stage B from Wt[n][k]
            const unsigned short* wp = Wt + (size_t)(n0 + br) * DMODEL + k0 + bqr;
            uint4 b0 = *(const uint4*)wp;
            uint4 b1 = *(const uint4*)(wp + 8);
            *(uint4*)&Bs[br][bqr]     = b0;
            *(uint4*)&Bs[br][bqr + 8] = b1;
        }
        __syncthreads();
        #pragma unroll
        for (int s = 0; s < 2; ++s) {
            bf16x8 af[2];
            #pragma unroll
            for (int i = 0; i < 2; ++i)
                af[i] = *(const bf16x8*)&As[wave * 32 + i * 16 + lrow][s * 32 + quad * 8];
            #pragma unroll
            for (int n = 0; n < 4; ++n) {
                bf16x8 bf = *(const bf16x8*)&Bs[n * 16 + lrow][s * 32 + quad * 8];
                acc[0][n] = __builtin_amdgcn_mfma_f32_16x16x32_bf16(af[0], bf, acc[0][n], 0, 0, 0);
                acc[1][n] = __builtin_amdgcn_mfma_f32_16x16x32_bf16(af[1], bf, acc[1][n], 0, 0, 0);
            }
        }
    }

    #pragma unroll
    for (int n = 0; n < 4; ++n) {
        const int col = n0 + n * 16 + lrow;
        const float bv_ = bo[col];
        #pragma unroll
        for (int i = 0; i < 2; ++i) {
            #pragma unroll
            for (int r = 0; r < 4; ++r) {
                const int m = m0 + wave * 32 + i * 16 + quad * 4 + r;
                out[(size_t)m * DMODEL + col] = acc[i][n][r] + bv_;
            }
        }
    }
}

// ---------------------------------------------------------------------------
extern "C" void kernel_launch(void* const* d_in, const int* in_sizes, int n_in,
                              void* d_out, int out_size, void* d_ws, size_t ws_size,
                              hipStream_t stream)
{
    const float* qin = (const float*)d_in[0];
    const float* kin = (const float*)d_in[1];
    const float* vin = (const float*)d_in[2];
    const float* Wq  = (const float*)d_in[3];
    const float* bq  = (const float*)d_in[4];
    const float* Wk  = (const float*)d_in[5];
    const float* bk  = (const float*)d_in[6];
    const float* Wv  = (const float*)d_in[7];
    const float* bv  = (const float*)d_in[8];
    const float* Wo  = (const float*)d_in[9];
    const float* bo  = (const float*)d_in[10];

    unsigned short* ws = (unsigned short*)d_ws;
    float* out = (float*)d_out;

    dim3 gw(DMODEL / 32, DMODEL / 32, 4);
    wt_prep_kernel<<<gw, 256, 0, stream>>>(Wq, Wk, Wv, Wo, ws + WS_WT);

    dim3 gp(DMODEL / 128, MTOT / 128, 3);
    qkv_mfma_kernel<<<gp, 256, 0, stream>>>(qin, kin, vin, bq, bk, bv, ws);

    dim3 ga(BATCH * NH, SEQ / 64);
    attn_mfma_kernel<<<ga, 256, 0, stream>>>(ws, ws + WS_CTX);

    dim3 go(DMODEL / 64, MTOT / 128);
    out_proj_mfma_kernel<<<go, 256, 0, stream>>>(ws, bo, out);
}

// Round 4
// 172.020 us; speedup vs baseline: 3.3948x; 1.0895x over previous
//
#include <hip/hip_runtime.h>
#include <math.h>

#define BATCH 2
#define SEQ 2048
#define DMODEL 512
#define NH 8
#define HDIM 64
#define MTOT (BATCH * SEQ)              // 4096
#define QSIZE (BATCH * NH * SEQ * HDIM) // 2097152 elems per tensor
#define WSIZE (DMODEL * DMODEL)         // 262144 elems per weight

typedef __attribute__((ext_vector_type(8))) short bf16x8;
typedef __attribute__((ext_vector_type(4))) float f32x4;

__device__ inline unsigned short f2bf(float f) {
    union { float f; unsigned u; } v; v.f = f;
    unsigned u = v.u;
    u += 0x7fffu + ((u >> 16) & 1u);
    return (unsigned short)(u >> 16);
}
__device__ inline unsigned pack2(float lo, float hi) {
    return (unsigned)f2bf(lo) | ((unsigned)f2bf(hi) << 16);
}

// LDS row stride: 72 elems = 144 B (16B-aligned for ds_read_b128).
#define LSTR 72

// ws layout (bf16 elems):
#define WS_Q   ((size_t)0)
#define WS_K   ((size_t)QSIZE)
#define WS_V   (2 * (size_t)QSIZE)        // [B,H,HD,S] transposed
#define WS_CTX (3 * (size_t)QSIZE)
#define WS_WT  (4 * (size_t)QSIZE)        // 4 transposed weights
#define WS_ABF (4 * (size_t)QSIZE + 4 * (size_t)WSIZE)  // bf16 inputs q,k,v

// ---------------------------------------------------------------------------
// Kernel 0a: transpose + bf16-convert the 4 weight matrices.
// ---------------------------------------------------------------------------
__global__ __launch_bounds__(256) void wt_prep_kernel(
    const float* __restrict__ Wq, const float* __restrict__ Wk,
    const float* __restrict__ Wv, const float* __restrict__ Wo,
    unsigned short* __restrict__ wt)
{
    const int z = blockIdx.z;
    const float* W = (z == 0) ? Wq : (z == 1) ? Wk : (z == 2) ? Wv : Wo;
    unsigned short* Wt = wt + (size_t)z * WSIZE;

    __shared__ float T[32][33];
    const int tid = threadIdx.x;
    const int k0 = blockIdx.x * 32, n0 = blockIdx.y * 32;

    {
        int r = tid >> 3, c = (tid & 7) * 4;
        float4 v = *(const float4*)&W[(size_t)(k0 + r) * DMODEL + n0 + c];
        T[r][c + 0] = v.x; T[r][c + 1] = v.y; T[r][c + 2] = v.z; T[r][c + 3] = v.w;
    }
    __syncthreads();
    {
        int n = tid >> 3, c = (tid & 7) * 4;
        uint2 o;
        o.x = pack2(T[c + 0][n], T[c + 1][n]);
        o.y = pack2(T[c + 2][n], T[c + 3][n]);
        *(uint2*)&Wt[(size_t)(n0 + n) * DMODEL + k0 + c] = o;
    }
}

// ---------------------------------------------------------------------------
// Kernel 0b: convert fp32 inputs -> bf16 (row-major unchanged layout).
// grid (QSIZE/2048 = 1024, 3); 8 elems/thread.
// ---------------------------------------------------------------------------
__global__ __launch_bounds__(256) void inp_prep_kernel(
    const float* __restrict__ qin, const float* __restrict__ kin,
    const float* __restrict__ vin, unsigned short* __restrict__ abf)
{
    const int z = blockIdx.y;
    const float* src = (z == 0) ? qin : (z == 1) ? kin : vin;
    unsigned short* dst = abf + (size_t)z * QSIZE;

    const size_t i = ((size_t)blockIdx.x * 256 + threadIdx.x) * 8;
    float4 f0 = *(const float4*)(src + i);
    float4 f1 = *(const float4*)(src + i + 4);
    uint4 o;
    o.x = pack2(f0.x, f0.y); o.y = pack2(f0.z, f0.w);
    o.z = pack2(f1.x, f1.y); o.w = pack2(f1.z, f1.w);
    *(uint4*)(dst + i) = o;
}

// ---------------------------------------------------------------------------
// Kernel 1: fused QKV projection, bf16 MFMA, 128x128 tiles, bf16 A input.
// Q scaled by 0.125. Q,K stored [B,H,S,HD]; V stored [B,H,HD,S].
// ---------------------------------------------------------------------------
__global__ __launch_bounds__(256) void qkv_mfma_kernel(
    unsigned short* __restrict__ ws,
    const float* __restrict__ bq, const float* __restrict__ bk,
    const float* __restrict__ bv)
{
    const int which = blockIdx.z;
    const unsigned short* A  = ws + WS_ABF + (size_t)which * QSIZE;
    const unsigned short* Wt = ws + WS_WT + (size_t)which * WSIZE;
    const float* bias = (which == 0) ? bq : (which == 1) ? bk : bv;
    unsigned short* out = ws + (size_t)which * QSIZE;

    __shared__ __align__(16) short As[128][LSTR];
    __shared__ __align__(16) short Bs[128][LSTR];

    const int tid = threadIdx.x;
    const int lane = tid & 63, wave = tid >> 6;
    const int lrow = lane & 15, quad = lane >> 4;
    const int m0 = blockIdx.y * 128, n0 = blockIdx.x * 128;

    const int sr = tid >> 1;             // staging row 0..127
    const int sh = (tid & 1) * 32;       // col half (elems)

    f32x4 acc[2][8];
    #pragma unroll
    for (int i = 0; i < 2; ++i)
        #pragma unroll
        for (int n = 0; n < 8; ++n) acc[i][n] = f32x4{0.f, 0.f, 0.f, 0.f};

    for (int k0 = 0; k0 < DMODEL; k0 += 64) {
        __syncthreads();
        {   // stage A: straight bf16 copy
            const unsigned short* ap = A + (size_t)(m0 + sr) * DMODEL + k0 + sh;
            uint4 a0 = *(const uint4*)(ap + 0),  a1 = *(const uint4*)(ap + 8);
            uint4 a2 = *(const uint4*)(ap + 16), a3 = *(const uint4*)(ap + 24);
            *(uint4*)&As[sr][sh + 0]  = a0;
            *(uint4*)&As[sr][sh + 8]  = a1;
            *(uint4*)&As[sr][sh + 16] = a2;
            *(uint4*)&As[sr][sh + 24] = a3;
        }
        {   // stage B: straight bf16 copy from Wt[n][k]
            const unsigned short* wp = Wt + (size_t)(n0 + sr) * DMODEL + k0 + sh;
            uint4 b0 = *(const uint4*)(wp + 0),  b1 = *(const uint4*)(wp + 8);
            uint4 b2 = *(const uint4*)(wp + 16), b3 = *(const uint4*)(wp + 24);
            *(uint4*)&Bs[sr][sh + 0]  = b0;
            *(uint4*)&Bs[sr][sh + 8]  = b1;
            *(uint4*)&Bs[sr][sh + 16] = b2;
            *(uint4*)&Bs[sr][sh + 24] = b3;
        }
        __syncthreads();
        #pragma unroll
        for (int s = 0; s < 2; ++s) {
            bf16x8 af[2];
            #pragma unroll
            for (int i = 0; i < 2; ++i)
                af[i] = *(const bf16x8*)&As[wave * 32 + i * 16 + lrow][s * 32 + quad * 8];
            #pragma unroll
            for (int n = 0; n < 8; ++n) {
                bf16x8 bf = *(const bf16x8*)&Bs[n * 16 + lrow][s * 32 + quad * 8];
                acc[0][n] = __builtin_amdgcn_mfma_f32_16x16x32_bf16(af[0], bf, acc[0][n], 0, 0, 0);
                acc[1][n] = __builtin_amdgcn_mfma_f32_16x16x32_bf16(af[1], bf, acc[1][n], 0, 0, 0);
            }
        }
    }

    if (which < 2) {
        const float scale = (which == 0) ? 0.125f : 1.0f;
        #pragma unroll
        for (int n = 0; n < 8; ++n) {
            const int col = n0 + n * 16 + lrow;
            const int h_ = col >> 6, hd_ = col & 63;
            const float bv_ = bias[col];
            #pragma unroll
            for (int i = 0; i < 2; ++i) {
                #pragma unroll
                for (int r = 0; r < 4; ++r) {
                    const int m = m0 + wave * 32 + i * 16 + quad * 4 + r;
                    const int b_ = m >> 11, s_ = m & (SEQ - 1);
                    const float v = (acc[i][n][r] + bv_) * scale;
                    out[((size_t)((b_ * NH + h_) * SEQ + s_)) * HDIM + hd_] = f2bf(v);
                }
            }
        }
    } else {
        #pragma unroll
        for (int n = 0; n < 8; ++n) {
            const int col = n0 + n * 16 + lrow;
            const int h_ = col >> 6, hd_ = col & 63;
            const float bv_ = bias[col];
            #pragma unroll
            for (int i = 0; i < 2; ++i) {
                const int m = m0 + wave * 32 + i * 16 + quad * 4;
                const int b_ = m >> 11, s_ = m & (SEQ - 1);
                uint2 o;
                o.x = pack2(acc[i][n][0] + bv_, acc[i][n][1] + bv_);
                o.y = pack2(acc[i][n][2] + bv_, acc[i][n][3] + bv_);
                *(uint2*)&out[((size_t)((b_ * NH + h_) * HDIM + hd_)) * SEQ + s_] = o;
            }
        }
    }
}

// ---------------------------------------------------------------------------
// Kernel 2: bf16 MFMA flash attention, S^T formulation.
// S^T = K·Q^T  (C-layout: col = q, row = key) -> each lane owns ONE q row;
// softmax reduce = in-register 16 + 2 shfl_xor. O^T = V^T·P^T keeps q on
// cols; alpha/l are per-lane scalars. Ps/ctx writes vectorized.
// grid = (B*H = 16, S/64 = 32), 256 thr.
// ---------------------------------------------------------------------------
__global__ __launch_bounds__(256) void attn_mfma_kernel(
    const unsigned short* __restrict__ ws, unsigned short* __restrict__ ctx)
{
    const unsigned short* Q = ws + WS_Q;   // pre-scaled by 0.125
    const unsigned short* K = ws + WS_K;
    const unsigned short* V = ws + WS_V;   // [B,H,HD,S]

    __shared__ __align__(16) short Ks[64][LSTR];  // K[key][hd]
    __shared__ __align__(16) short Vt[64][LSTR];  // V^T[hd][key]
    __shared__ __align__(16) short Ps[64][LSTR];  // P[q][key] (per-wave rows)

    const int bh = blockIdx.x;
    const int q0 = blockIdx.y * 64;
    const int tid = threadIdx.x;
    const int lane = tid & 63, wave = tid >> 6;
    const int lrow = lane & 15, quad = lane >> 4;
    const size_t base = (size_t)bh * SEQ * HDIM;

    // Q as B-operand fragments: B[k=d][n=q]; lane supplies Q[q=lrow][d=quad*8+j]
    const unsigned short* qrow = Q + base + (size_t)(q0 + wave * 16 + lrow) * HDIM;
    const bf16x8 qb0 = *(const bf16x8*)(qrow + quad * 8);
    const bf16x8 qb1 = *(const bf16x8*)(qrow + 32 + quad * 8);

    float m_prev = -1e30f, l_run = 0.f;
    f32x4 oacc[4];   // O^T: acc[n] rows d = n*16+quad*4+r, col q = lrow
    #pragma unroll
    for (int n = 0; n < 4; ++n) oacc[n] = f32x4{0.f, 0.f, 0.f, 0.f};

    const int kr = tid >> 2, kc = (tid & 3) * 16;
    const int vr = tid >> 2, vq = (tid & 3) * 16;

    for (int kt = 0; kt < SEQ; kt += 64) {
        __syncthreads();
        {   // stage K row-major
            const unsigned short* kp = K + base + (size_t)(kt + kr) * HDIM + kc;
            uint4 k0 = *(const uint4*)kp;
            uint4 k1 = *(const uint4*)(kp + 8);
            *(uint4*)&Ks[kr][kc]     = k0;
            *(uint4*)&Ks[kr][kc + 8] = k1;
        }
        {   // stage Vt straight copy
            const unsigned short* vp = V + base + (size_t)vr * SEQ + kt + vq;
            uint4 v0 = *(const uint4*)vp;
            uint4 v1 = *(const uint4*)(vp + 8);
            *(uint4*)&Vt[vr][vq]     = v0;
            *(uint4*)&Vt[vr][vq + 8] = v1;
        }
        __syncthreads();

        // ---- S^T = K·Q^T : st[n] holds keys n*16+quad*4+r, q = lrow ----
        f32x4 st[4];
        #pragma unroll
        for (int n = 0; n < 4; ++n) {
            bf16x8 ka0 = *(const bf16x8*)&Ks[n * 16 + lrow][quad * 8];
            bf16x8 ka1 = *(const bf16x8*)&Ks[n * 16 + lrow][32 + quad * 8];
            f32x4 z = f32x4{0.f, 0.f, 0.f, 0.f};
            z = __builtin_amdgcn_mfma_f32_16x16x32_bf16(ka0, qb0, z, 0, 0, 0);
            z = __builtin_amdgcn_mfma_f32_16x16x32_bf16(ka1, qb1, z, 0, 0, 0);
            st[n] = z;
        }

        // ---- softmax for q = lrow: all 16 scores are in-lane ----
        float tmax = st[0][0];
        #pragma unroll
        for (int n = 0; n < 4; ++n)
            #pragma unroll
            for (int r = 0; r < 4; ++r) tmax = fmaxf(tmax, st[n][r]);
        tmax = fmaxf(tmax, __shfl_xor(tmax, 16));
        tmax = fmaxf(tmax, __shfl_xor(tmax, 32));

        const float mnew = fmaxf(m_prev, tmax);
        const float alpha = __expf(m_prev - mnew);
        float p[4][4];
        float tsum = 0.f;
        #pragma unroll
        for (int n = 0; n < 4; ++n)
            #pragma unroll
            for (int r = 0; r < 4; ++r) {
                p[n][r] = __expf(st[n][r] - mnew);
                tsum += p[n][r];
            }
        tsum += __shfl_xor(tsum, 16);
        tsum += __shfl_xor(tsum, 32);
        l_run = l_run * alpha + tsum;
        m_prev = mnew;
        #pragma unroll
        for (int n = 0; n < 4; ++n) {
            oacc[n][0] *= alpha; oacc[n][1] *= alpha;
            oacc[n][2] *= alpha; oacc[n][3] *= alpha;
        }
        // write P[q][key]: row = wave*16+lrow, cols n*16+quad*4 (+0..3)
        #pragma unroll
        for (int n = 0; n < 4; ++n) {
            uint2 o;
            o.x = pack2(p[n][0], p[n][1]);
            o.y = pack2(p[n][2], p[n][3]);
            *(uint2*)&Ps[wave * 16 + lrow][n * 16 + quad * 4] = o;
        }
        // Ps rows are wave-private: no barrier (lgkmcnt ordering suffices).

        // ---- O^T += V^T·P^T ----
        bf16x8 pb0 = *(const bf16x8*)&Ps[wave * 16 + lrow][quad * 8];
        bf16x8 pb1 = *(const bf16x8*)&Ps[wave * 16 + lrow][32 + quad * 8];
        #pragma unroll
        for (int n = 0; n < 4; ++n) {
            bf16x8 va0 = *(const bf16x8*)&Vt[n * 16 + lrow][quad * 8];
            bf16x8 va1 = *(const bf16x8*)&Vt[n * 16 + lrow][32 + quad * 8];
            oacc[n] = __builtin_amdgcn_mfma_f32_16x16x32_bf16(va0, pb0, oacc[n], 0, 0, 0);
            oacc[n] = __builtin_amdgcn_mfma_f32_16x16x32_bf16(va1, pb1, oacc[n], 0, 0, 0);
        }
    }

    // ---- epilogue: normalize, vectorized bf16 ctx [B,S,D] ----
    const int b_ = bh >> 3, h_ = bh & 7;
    const float inv = 1.f / l_run;
    const int qg = q0 + wave * 16 + lrow;
    unsigned short* crow = ctx + ((size_t)(b_ * SEQ + qg)) * DMODEL + h_ * HDIM;
    #pragma unroll
    for (int n = 0; n < 4; ++n) {
        uint2 o;
        o.x = pack2(oacc[n][0] * inv, oacc[n][1] * inv);
        o.y = pack2(oacc[n][2] * inv, oacc[n][3] * inv);
        *(uint2*)&crow[n * 16 + quad * 4] = o;
    }
}

// ---------------------------------------------------------------------------
// Kernel 3: output projection, bf16 MFMA, 128x64 tiles.
// ---------------------------------------------------------------------------
__global__ __launch_bounds__(256) void out_proj_mfma_kernel(
    const unsigned short* __restrict__ ws, const float* __restrict__ bo,
    float* __restrict__ out)
{
    const unsigned short* ctx = ws + WS_CTX;
    const unsigned short* Wt  = ws + WS_WT + 3 * (size_t)WSIZE;

    __shared__ __align__(16) short As[128][LSTR];
    __shared__ __align__(16) short Bs[64][LSTR];

    const int tid = threadIdx.x;
    const int lane = tid & 63, wave = tid >> 6;
    const int lrow = lane & 15, quad = lane >> 4;
    const int m0 = blockIdx.y * 128, n0 = blockIdx.x * 64;

    const int sr = tid >> 1, sh = (tid & 1) * 32;
    const int br = tid >> 2, bqr = (tid & 3) * 16;

    f32x4 acc[2][4];
    #pragma unroll
    for (int i = 0; i < 2; ++i)
        #pragma unroll
        for (int n = 0; n < 4; ++n) acc[i][n] = f32x4{0.f, 0.f, 0.f, 0.f};

    for (int k0 = 0; k0 < DMODEL; k0 += 64) {
        __syncthreads();
        {
            const unsigned short* ap = ctx + (size_t)(m0 + sr) * DMODEL + k0 + sh;
            uint4 c0 = *(const uint4*)(ap + 0),  c1 = *(const uint4*)(ap + 8);
            uint4 c2 = *(const uint4*)(ap + 16), c3 = *(const uint4*)(ap + 24);
            *(uint4*)&As[sr][sh + 0]  = c0;
            *(uint4*)&As[sr][sh + 8]  = c1;
            *(uint4*)&As[sr][sh + 16] = c2;
            *(uint4*)&As[sr][sh + 24] = c3;
        }
        {
            const unsigned short* wp = Wt + (size_t)(n0 + br) * DMODEL + k0 + bqr;
            uint4 b0 = *(const uint4*)wp;
            uint4 b1 = *(const uint4*)(wp + 8);
            *(uint4*)&Bs[br][bqr]     = b0;
            *(uint4*)&Bs[br][bqr + 8] = b1;
        }
        __syncthreads();
        #pragma unroll
        for (int s = 0; s < 2; ++s) {
            bf16x8 af[2];
            #pragma unroll
            for (int i = 0; i < 2; ++i)
                af[i] = *(const bf16x8*)&As[wave * 32 + i * 16 + lrow][s * 32 + quad * 8];
            #pragma unroll
            for (int n = 0; n < 4; ++n) {
                bf16x8 bf = *(const bf16x8*)&Bs[n * 16 + lrow][s * 32 + quad * 8];
                acc[0][n] = __builtin_amdgcn_mfma_f32_16x16x32_bf16(af[0], bf, acc[0][n], 0, 0, 0);
                acc[1][n] = __builtin_amdgcn_mfma_f32_16x16x32_bf16(af[1], bf, acc[1][n], 0, 0, 0);
            }
        }
    }

    #pragma unroll
    for (int n = 0; n < 4; ++n) {
        const int col = n0 + n * 16 + lrow;
        const float bv_ = bo[col];
        #pragma unroll
        for (int i = 0; i < 2; ++i) {
            #pragma unroll
            for (int r = 0; r < 4; ++r) {
                const int m = m0 + wave * 32 + i * 16 + quad * 4 + r;
                out[(size_t)m * DMODEL + col] = acc[i][n][r] + bv_;
            }
        }
    }
}

// ---------------------------------------------------------------------------
extern "C" void kernel_launch(void* const* d_in, const int* in_sizes, int n_in,
                              void* d_out, int out_size, void* d_ws, size_t ws_size,
                              hipStream_t stream)
{
    const float* qin = (const float*)d_in[0];
    const float* kin = (const float*)d_in[1];
    const float* vin = (const float*)d_in[2];
    const float* Wq  = (const float*)d_in[3];
    const float* bq  = (const float*)d_in[4];
    const float* Wk  = (const float*)d_in[5];
    const float* bk  = (const float*)d_in[6];
    const float* Wv  = (const float*)d_in[7];
    const float* bv  = (const float*)d_in[8];
    const float* Wo  = (const float*)d_in[9];
    const float* bo  = (const float*)d_in[10];

    unsigned short* ws = (unsigned short*)d_ws;
    float* out = (float*)d_out;

    dim3 gw(DMODEL / 32, DMODEL / 32, 4);
    wt_prep_kernel<<<gw, 256, 0, stream>>>(Wq, Wk, Wv, Wo, ws + WS_WT);

    dim3 gi(QSIZE / (256 * 8), 3);
    inp_prep_kernel<<<gi, 256, 0, stream>>>(qin, kin, vin, ws + WS_ABF);

    dim3 gp(DMODEL / 128, MTOT / 128, 3);
    qkv_mfma_kernel<<<gp, 256, 0, stream>>>(ws, bq, bk, bv);

    dim3 ga(BATCH * NH, SEQ / 64);
    attn_mfma_kernel<<<ga, 256, 0, stream>>>(ws, ws + WS_CTX);

    dim3 go(DMODEL / 64, MTOT / 128);
    out_proj_mfma_kernel<<<go, 256, 0, stream>>>(ws, bo, out);
}